// Round 4
// baseline (14470.508 us; speedup 1.0000x reference)
//
#include <hip/hip_runtime.h>
#include <cstddef>
#include <cstdint>

#define LAT 512
#define HID 1024
#define NSLOT 16
#define NB 256
#define HOR 64
#define NBLK 256

using short8  = __attribute__((ext_vector_type(8))) short;
using floatx4 = __attribute__((ext_vector_type(4))) float;

__device__ __forceinline__ float sigmoid_f(float x) { return 1.0f / (1.0f + __expf(-x)); }
__device__ __forceinline__ float tanh_f(float x) {
    float e = __expf(2.0f * x);
    return 1.0f - 2.0f / (e + 1.0f);
}
__device__ __forceinline__ unsigned short f2bf(float f) {
    union { float f; uint32_t u; } v; v.f = f;
    uint32_t u = v.u;
    return (unsigned short)((u + 0x7fffu + ((u >> 16) & 1u)) >> 16);
}
__device__ __forceinline__ floatx4 sig4(floatx4 x) {
    floatx4 r; r[0]=sigmoid_f(x[0]); r[1]=sigmoid_f(x[1]); r[2]=sigmoid_f(x[2]); r[3]=sigmoid_f(x[3]); return r;
}
__device__ __forceinline__ floatx4 tanh4(floatx4 x) {
    floatx4 r; r[0]=tanh_f(x[0]); r[1]=tanh_f(x[1]); r[2]=tanh_f(x[2]); r[3]=tanh_f(x[3]); return r;
}
__device__ __forceinline__ void store_bf4(unsigned short* p, floatx4 v) {
    union { unsigned short u[4]; uint2 v2; } o;
    o.u[0]=f2bf(v[0]); o.u[1]=f2bf(v[1]); o.u[2]=f2bf(v[2]); o.u[3]=f2bf(v[3]);
    *(uint2*)p = o.v2;
}
// async global->LDS, 16B per lane. LDS dest is wave-uniform base + lane*16.
__device__ __forceinline__ void async16(const void* g, void* l) {
    __builtin_amdgcn_global_load_lds(
        (const __attribute__((address_space(1))) unsigned int*)(unsigned long long)g,
        (__attribute__((address_space(3))) unsigned int*)(unsigned int)(unsigned long long)l,
        16, 0, 0);
}

// Manual grid barrier: device-scope atomics (cross-XCD safe via agent-scope
// acq/rel — per Guideline 16). Requires all blocks co-resident: grid=256
// blocks x 256 thr x 32KB LDS -> >=1 block/CU everywhere, capacity >> grid.
__device__ __forceinline__ void grid_bar(unsigned* cnt, unsigned* gen)
{
    __syncthreads();
    if (threadIdx.x == 0) {
        const unsigned g = __hip_atomic_load(gen, __ATOMIC_RELAXED, __HIP_MEMORY_SCOPE_AGENT);
        const unsigned a = __hip_atomic_fetch_add(cnt, 1u, __ATOMIC_ACQ_REL, __HIP_MEMORY_SCOPE_AGENT);
        if (a == NBLK - 1u) {
            __hip_atomic_store(cnt, 0u, __ATOMIC_RELAXED, __HIP_MEMORY_SCOPE_AGENT);
            __hip_atomic_fetch_add(gen, 1u, __ATOMIC_ACQ_REL, __HIP_MEMORY_SCOPE_AGENT);
        } else {
            while (__hip_atomic_load(gen, __ATOMIC_ACQUIRE, __HIP_MEMORY_SCOPE_AGENT) == g)
                __builtin_amdgcn_s_sleep(2);
        }
    }
    __syncthreads();
}

// ---------------------------------------------------------------------------
// MFMA GEMM core: acc = A[m0:m0+BM, kbeg:kend] * W[n0:n0+BN, kbeg:kend]^T
// 256 threads = 4 waves (2x2), 16x16x32 bf16 MFMA, BK=64, async staging with
// XOR-chunk swizzle. Both A and W K-contiguous bf16.
// ---------------------------------------------------------------------------
template<int BM, int BN>
__device__ __forceinline__ void gemm_core(
    short* __restrict__ smem,
    const unsigned short* __restrict__ A, int lda,
    const unsigned short* __restrict__ W, int ldw,
    int m0, int n0, int kbeg, int kend,
    floatx4 (&acc)[BM/32][BN/32])
{
    constexpr int TM = BM/32, TN = BN/32;
    short* As = smem;
    short* Bs = smem + BM*64;
    const int t    = threadIdx.x;
    const int lane = t & 63;
    const int w    = t >> 6;
    const int wm   = w >> 1, wn = w & 1;
    const int r8 = lane >> 3;
    const int cx = (lane & 7) ^ r8;   // chunk c stored at in-row slot c^row
    const int q  = lane >> 4;
    const int ml = lane & 15;

    const floatx4 zf = {0.f,0.f,0.f,0.f};
    #pragma unroll
    for (int i = 0; i < TM; ++i)
        #pragma unroll
        for (int j = 0; j < TN; ++j) acc[i][j] = zf;

    for (int k0 = kbeg; k0 < kend; k0 += 64) {
        __syncthreads();
        #pragma unroll
        for (int u = 0; u < BM/32; ++u) {
            const int row = w*(BM/4) + u*8;
            async16(A + (size_t)(m0+row+r8)*lda + k0 + cx*8, &As[row*64]);
        }
        #pragma unroll
        for (int u = 0; u < BN/32; ++u) {
            const int row = w*(BN/4) + u*8;
            async16(W + (size_t)(n0+row+r8)*ldw + k0 + cx*8, &Bs[row*64]);
        }
        __syncthreads();
        #pragma unroll
        for (int s2 = 0; s2 < 2; ++s2) {
            short8 af[TM], bfr[TN];
            #pragma unroll
            for (int i = 0; i < TM; ++i) {
                const int m = wm*(BM/2) + i*16 + ml;
                af[i] = *(const short8*)&As[(m*8 + ((s2*4+q) ^ (m&7)))*8];
            }
            #pragma unroll
            for (int j = 0; j < TN; ++j) {
                const int n = wn*(BN/2) + j*16 + ml;
                bfr[j] = *(const short8*)&Bs[(n*8 + ((s2*4+q) ^ (n&7)))*8];
            }
            #pragma unroll
            for (int i = 0; i < TM; ++i)
                #pragma unroll
                for (int j = 0; j < TN; ++j)
                    acc[i][j] = __builtin_amdgcn_mfma_f32_16x16x32_bf16(af[i], bfr[j], acc[i][j], 0, 0, 0);
        }
    }
}

template<int BM, int BN>
__device__ __forceinline__ void store_partial(
    floatx4 (&acc)[BM/32][BN/32], float* __restrict__ dst, int ldc, int m0, int n0)
{
    const int lane = threadIdx.x & 63;
    const int w    = threadIdx.x >> 6;
    const int wm = w>>1, wn = w&1;
    const int q = lane>>4, ml = lane&15;
    const int gmb = m0 + wm*(BM/2) + q*4;
    const int gnb = n0 + wn*(BN/2) + ml;
    #pragma unroll
    for (int i = 0; i < BM/32; ++i)
        #pragma unroll
        for (int j = 0; j < BN/32; ++j) {
            const int gm = gmb + i*16, gn = gnb + j*16;
            #pragma unroll
            for (int r = 0; r < 4; ++r)
                dst[(size_t)(gm+r)*ldc + gn] = acc[i][j][r];
        }
}

// LSTM pointwise: sum 4 split-K partials + biases; h -> bf16 to 1-2 dests.
__device__ __forceinline__ void pw_phase(
    const float* __restrict__ gP, long long zMN,
    const float* __restrict__ bih, const float* __restrict__ bhh,
    const float* __restrict__ bc,
    float* __restrict__ c,
    unsigned short* __restrict__ h1d, int ld1,
    unsigned short* __restrict__ h2d, int ld2)
{
    const int idx = (blockIdx.x*256 + threadIdx.x) << 2;   // < NB*HID
    const int b = idx >> 10;
    const int j = idx & 1023;
    floatx4 g[4];
    #pragma unroll
    for (int gi = 0; gi < 4; ++gi) {
        g[gi] = *(const floatx4*)(bih + gi*HID + j) + *(const floatx4*)(bhh + gi*HID + j);
        if (bc) g[gi] += *(const floatx4*)(bc + gi*HID + j);
    }
    const float* base = gP + (long long)b*4*HID + j;
    #pragma unroll
    for (int z = 0; z < 4; ++z) {
        const float* p = base + z*zMN;
        #pragma unroll
        for (int gi = 0; gi < 4; ++gi) g[gi] += *(const floatx4*)(p + gi*HID);
    }
    const floatx4 i_ = sig4(g[0]), f_ = sig4(g[1]), gg = tanh4(g[2]), o_ = sig4(g[3]);
    const floatx4 cv = *(const floatx4*)(c + idx);
    const floatx4 cn = f_*cv + i_*gg;
    *(floatx4*)(c + idx) = cn;
    const floatx4 hv = o_ * tanh4(cn);
    store_bf4(h1d + (size_t)b*ld1 + j, hv);
    if (h2d) store_bf4(h2d + (size_t)b*ld2 + j, hv);
}

// O1 reduce: sum 4 partials + bias, relu, bf16 -> T[(b*HOR+s)] and th0 t-half
__device__ __forceinline__ void o1red_phase(
    const float* __restrict__ oP, const float* __restrict__ b1,
    unsigned short* __restrict__ T, int s, unsigned short* __restrict__ th0)
{
    const int idx = (blockIdx.x*256 + threadIdx.x) << 2;   // < NB*HID
    const int b = idx >> 10;
    const int j = idx & 1023;
    floatx4 a = *(const floatx4*)(b1 + j);
    #pragma unroll
    for (int z = 0; z < 4; ++z) a += *(const floatx4*)(oP + (long long)z*(NB*HID) + idx);
    #pragma unroll
    for (int c2 = 0; c2 < 4; ++c2) a[c2] = fmaxf(a[c2], 0.f);
    store_bf4(T + ((size_t)b*HOR + s)*HID + j, a);
    store_bf4(th0 + (size_t)b*2048 + j, a);
}

struct RP {
    const unsigned short *xh0, *Wg0, *Wg0c, *Wg1, *Wo1;
    unsigned short *th0, *hh1, *T;
    float *gP, *oP, *c0, *c1;
    const float *bih0, *bhh0, *bih1, *bhh1, *bc, *ob1;
    unsigned *cnt, *gen;
};

// Persistent kernel: the entire 64-step LSTM rollout, manual grid barrier.
// Grid MUST be 256 blocks x 256 threads.
__global__ __launch_bounds__(256)
void rollout(RP P)
{
    __shared__ short smem[256*64];   // 32 KB, shared across phases
    const int bid = blockIdx.x;
    const long long zMN = (long long)NB * 4 * HID;
    floatx4 acc[4][4];

    for (int s = 0; s < HOR; ++s) {
        // P1: gates0. s=0: [prior|h0] @ [Wih0|Whh0]^T (K=1536)
        //            s>0: [t|h0] @ [Wc|Whh0]^T (K=2048). split-K=4.
        {
            const int z = bid & 3, nt = (bid>>2) & 31, mt = bid >> 7;
            if (s == 0)
                gemm_core<128,128>(smem, P.xh0, 1536, P.Wg0, 1536, mt*128, nt*128, z*384, z*384+384, acc);
            else
                gemm_core<128,128>(smem, P.th0, 2048, P.Wg0c, 2048, mt*128, nt*128, z*512, z*512+512, acc);
            store_partial<128,128>(acc, P.gP + (long long)z*zMN, 4*HID, mt*128, nt*128);
        }
        grid_bar(P.cnt, P.gen);
        // P2: pw0 -> h0 into th0 right half + hh1 left half; c0 update
        pw_phase(P.gP, zMN, P.bih0, P.bhh0, s ? P.bc : nullptr, P.c0,
                 P.th0 + 1024, 2048, P.hh1, 2048);
        grid_bar(P.cnt, P.gen);
        // P3: gates1 = [h0|h1] @ [Wih1|Whh1]^T (K=2048), split-K=4
        {
            const int z = bid & 3, nt = (bid>>2) & 31, mt = bid >> 7;
            gemm_core<128,128>(smem, P.hh1, 2048, P.Wg1, 2048, mt*128, nt*128, z*512, z*512+512, acc);
            store_partial<128,128>(acc, P.gP + (long long)z*zMN, 4*HID, mt*128, nt*128);
        }
        grid_bar(P.cnt, P.gen);
        // P4: pw1 -> h1 into hh1 right half; c1 update
        pw_phase(P.gP, zMN, P.bih1, P.bhh1, nullptr, P.c1,
                 P.hh1 + 1024, 2048, nullptr, 0);
        grid_bar(P.cnt, P.gen);
        // P5: O1 partials: t_pre = h1 @ Wo1^T (K=1024), 64x64 tiles, split-K=4
        {
            const int z = bid & 3, nt = (bid>>2) & 15, mt = bid >> 6;
            floatx4 acc2[2][2];
            gemm_core<64,64>(smem, P.hh1 + 1024, 2048, P.Wo1, HID, mt*64, nt*64, z*256, z*256+256, acc2);
            store_partial<64,64>(acc2, P.oP + (long long)z*(NB*HID), HID, mt*64, nt*64);
        }
        grid_bar(P.cnt, P.gen);
        // P6: reduce + b1 + relu -> t (bf16) into T[b][s][:] and th0 left half
        o1red_phase(P.oP, P.ob1, P.T, s, P.th0);
        grid_bar(P.cnt, P.gen);
    }
}

// ---------------------------------------------------------------------------
// Standalone MFMA GEMM (one-shot uses): EPI 0: bf16 store, no bias (Wc);
// EPI 1: fp32 store + bias (final pred).
// ---------------------------------------------------------------------------
template<int BM, int BN, int EPI>
__global__ __launch_bounds__(256)
void mfma_std(const unsigned short* __restrict__ A, int lda,
              const unsigned short* __restrict__ W, int ldw, int K,
              const float* __restrict__ bias,
              float* __restrict__ Cf, int ldc,
              unsigned short* __restrict__ Cb, int ldcb)
{
    __shared__ short smem[(BM+BN)*64];
    floatx4 acc[BM/32][BN/32];
    const int m0 = blockIdx.y*BM, n0 = blockIdx.x*BN;
    gemm_core<BM,BN>(smem, A, lda, W, ldw, m0, n0, 0, K, acc);
    const int lane = threadIdx.x & 63;
    const int w    = threadIdx.x >> 6;
    const int wm = w>>1, wn = w&1;
    const int q = lane>>4, ml = lane&15;
    const int gmb = m0 + wm*(BM/2) + q*4;
    const int gnb = n0 + wn*(BN/2) + ml;
    #pragma unroll
    for (int i = 0; i < BM/32; ++i)
        #pragma unroll
        for (int j = 0; j < BN/32; ++j) {
            const int gm = gmb + i*16, gn = gnb + j*16;
            const float bv = (EPI == 1) ? bias[gn] : 0.f;
            #pragma unroll
            for (int r = 0; r < 4; ++r) {
                const float v = acc[i][j][r] + bv;
                if (EPI == 0) Cb[(size_t)(gm+r)*ldcb + gn] = f2bf(v);
                else          Cf[(size_t)(gm+r)*ldc  + gn] = v;
            }
        }
}

// pack fp32 [N,K] (contiguous) -> bf16 at d with leading dim ldd (K pow2)
__global__ __launch_bounds__(256)
void pack_mat(const float* __restrict__ s, unsigned short* __restrict__ d,
              int ldd, int kshift, int total)
{
    const int idx = blockIdx.x*256 + threadIdx.x;
    if (idx >= total) return;
    const int n = idx >> kshift;
    const int k = idx & ((1 << kshift) - 1);
    d[(size_t)n*ldd + k] = f2bf(s[idx]);
}

// op_W2 [512,1024] fp32 -> opW2T [1024,512] bf16
__global__ __launch_bounds__(256)
void tpose_pack(const float* __restrict__ s, unsigned short* __restrict__ d)
{
    const int idx = blockIdx.x*256 + threadIdx.x;   // < 1024*512
    const int h = idx >> 9;
    const int l = idx & 511;
    d[idx] = f2bf(s[(size_t)l*HID + h]);
}

// bc[n] = sum_l Wih0[n,l] * op_b2[l]
__global__ __launch_bounds__(256)
void bc_kernel(const float* __restrict__ wih0, const float* __restrict__ ob2,
               float* __restrict__ bc)
{
    const int n = blockIdx.x*256 + threadIdx.x;   // < 4096
    float a = 0.f;
    for (int l = 0; l < LAT; ++l) a += wih0[(size_t)n*LAT + l] * ob2[l];
    bc[n] = a;
}

// ---------------------------------------------------------------------------
// fp32 prologue GEMM (attention + prior), one-time. C2 = optional bf16 copy.
// ---------------------------------------------------------------------------
template<int RELU>
__global__ __launch_bounds__(256)
void gemm_tn(const float* __restrict__ A1, int lda1,
             const float* __restrict__ W1, int ldw1, int K1,
             const float* __restrict__ A2, int lda2,
             const float* __restrict__ W2, int ldw2, int K2,
             const float* __restrict__ bias1,
             float* __restrict__ C, int ldc,
             unsigned short* __restrict__ C2, int ldc2,
             int M, int N)
{
    __shared__ float As[16][64];
    __shared__ float Ws[16][64];
    const int t   = threadIdx.x;
    const int bn0 = blockIdx.x * 64;
    const int bm0 = blockIdx.y * 64;
    const int tx  = t & 15;
    const int ty  = t >> 4;
    const int lr  = t >> 2;
    const int lc  = (t & 3) << 2;

    float acc[4][4] = {};

    for (int src = 0; src < 2; ++src) {
        const float* A = src ? A2 : A1;
        if (!A) continue;
        const float* W = src ? W2 : W1;
        const int lda = src ? lda2 : lda1;
        const int ldw = src ? ldw2 : ldw1;
        const int K   = src ? K2 : K1;
        for (int k0 = 0; k0 < K; k0 += 16) {
            float4 av = make_float4(0.f, 0.f, 0.f, 0.f);
            const int am = bm0 + lr;
            if (am < M) av = *(const float4*)(A + (size_t)am * lda + k0 + lc);
            const float4 wv = *(const float4*)(W + (size_t)(bn0 + lr) * ldw + k0 + lc);
            __syncthreads();
            As[lc + 0][lr] = av.x; As[lc + 1][lr] = av.y;
            As[lc + 2][lr] = av.z; As[lc + 3][lr] = av.w;
            Ws[lc + 0][lr] = wv.x; Ws[lc + 1][lr] = wv.y;
            Ws[lc + 2][lr] = wv.z; Ws[lc + 3][lr] = wv.w;
            __syncthreads();
            #pragma unroll
            for (int kk = 0; kk < 16; ++kk) {
                const float4 a = *(const float4*)&As[kk][ty * 4];
                const float4 b = *(const float4*)&Ws[kk][tx * 4];
                const float ar[4] = {a.x, a.y, a.z, a.w};
                const float br[4] = {b.x, b.y, b.z, b.w};
                #pragma unroll
                for (int i = 0; i < 4; ++i)
                    #pragma unroll
                    for (int j = 0; j < 4; ++j)
                        acc[i][j] = fmaf(ar[i], br[j], acc[i][j]);
            }
        }
    }

    const int n0 = bn0 + tx * 4;
    float bv[4] = {0.f, 0.f, 0.f, 0.f};
    if (bias1) {
        #pragma unroll
        for (int j = 0; j < 4; ++j) bv[j] += bias1[n0 + j];
    }
    #pragma unroll
    for (int i = 0; i < 4; ++i) {
        const int m = bm0 + ty * 4 + i;
        if (m < M) {
            float ov[4];
            #pragma unroll
            for (int j = 0; j < 4; ++j) {
                float v = acc[i][j] + bv[j];
                if (RELU) v = fmaxf(v, 0.f);
                ov[j] = v;
            }
            *(float4*)(C + (size_t)m * ldc + n0) = make_float4(ov[0], ov[1], ov[2], ov[3]);
            if (C2) {
                #pragma unroll
                for (int j = 0; j < 4; ++j)
                    C2[(size_t)m * ldc2 + n0 + j] = f2bf(ov[j]);
            }
        }
    }
}

__global__ __launch_bounds__(256)
void attn_kernel(const float* __restrict__ q, const float* __restrict__ k,
                 const float* __restrict__ v, float* __restrict__ ctx)
{
    __shared__ float red[NSLOT][4];
    __shared__ float wts[NSLOT];
    const int b = blockIdx.x;
    const int t = threadIdx.x;
    const float4 qv = *(const float4*)(q + (size_t)b * HID + t * 4);
    #pragma unroll
    for (int s = 0; s < NSLOT; ++s) {
        const float4 kv = *(const float4*)(k + (size_t)s * HID + t * 4);
        float p = qv.x * kv.x + qv.y * kv.y + qv.z * kv.z + qv.w * kv.w;
        #pragma unroll
        for (int off = 32; off > 0; off >>= 1) p += __shfl_down(p, off);
        if ((t & 63) == 0) red[s][t >> 6] = p;
    }
    __syncthreads();
    if (t == 0) {
        float sc[NSLOT];
        float mx = -1e30f;
        for (int s = 0; s < NSLOT; ++s) {
            sc[s] = (red[s][0] + red[s][1] + red[s][2] + red[s][3]) * 0.03125f;
            mx = fmaxf(mx, sc[s]);
        }
        float sum = 0.f;
        for (int s = 0; s < NSLOT; ++s) { const float e = __expf(sc[s] - mx); wts[s] = e; sum += e; }
        const float inv = 1.f / sum;
        for (int s = 0; s < NSLOT; ++s) wts[s] *= inv;
    }
    __syncthreads();
    float4 a = make_float4(0.f, 0.f, 0.f, 0.f);
    #pragma unroll
    for (int s = 0; s < NSLOT; ++s) {
        const float wv = wts[s];
        const float4 vv = *(const float4*)(v + (size_t)s * HID + t * 4);
        a.x += wv * vv.x; a.y += wv * vv.y; a.z += wv * vv.z; a.w += wv * vv.w;
    }
    *(float4*)(ctx + (size_t)b * HID + t * 4) = a;
}

extern "C" void kernel_launch(void* const* d_in, const int* in_sizes, int n_in,
                              void* d_out, int out_size, void* d_ws, size_t ws_size,
                              hipStream_t stream)
{
    const float* cs    = (const float*)d_in[0];
    const float* mem   = (const float*)d_in[2];
    const float* q_W   = (const float*)d_in[3];
    const float* q_b   = (const float*)d_in[4];
    const float* k_W   = (const float*)d_in[5];
    const float* k_b   = (const float*)d_in[6];
    const float* v_W   = (const float*)d_in[7];
    const float* v_b   = (const float*)d_in[8];
    const float* mo_W  = (const float*)d_in[9];
    const float* mo_b  = (const float*)d_in[10];
    const float* pg_W1 = (const float*)d_in[11];
    const float* pg_b1 = (const float*)d_in[12];
    const float* pg_W2 = (const float*)d_in[13];
    const float* pg_b2 = (const float*)d_in[14];
    const float* w_ih0 = (const float*)d_in[15];
    const float* w_hh0 = (const float*)d_in[16];
    const float* b_ih0 = (const float*)d_in[17];
    const float* b_hh0 = (const float*)d_in[18];
    const float* w_ih1 = (const float*)d_in[19];
    const float* w_hh1 = (const float*)d_in[20];
    const float* b_ih1 = (const float*)d_in[21];
    const float* b_hh1 = (const float*)d_in[22];
    const float* op_W1 = (const float*)d_in[23];
    const float* op_b1 = (const float*)d_in[24];
    const float* op_W2 = (const float*)d_in[25];
    const float* op_b2 = (const float*)d_in[26];

    float* out       = (float*)d_out;                       // [256*64*512] preds
    float* prior_out = out + (size_t)NB * HOR * LAT;        // [256*512]

    char* base = (char*)d_ws;
    auto alloc = [&](size_t bytes) { char* r = base; base += (bytes + 255) & ~255ull; return r; };

    unsigned short* Wg0   = (unsigned short*)alloc((size_t)4*HID*(LAT+HID)*2);   // [4096][1536] = [Wih0|Whh0]
    unsigned short* Wg0c  = (unsigned short*)alloc((size_t)4*HID*(2*HID)*2);     // [4096][2048] = [Wc|Whh0]
    unsigned short* Wg1   = (unsigned short*)alloc((size_t)4*HID*(2*HID)*2);     // [4096][2048] = [Wih1|Whh1]
    unsigned short* Wo1   = (unsigned short*)alloc((size_t)HID*HID*2);           // [1024][1024]
    unsigned short* Wo2b  = (unsigned short*)alloc((size_t)LAT*HID*2);           // [512][1024]
    unsigned short* W2T   = (unsigned short*)alloc((size_t)HID*LAT*2);           // [1024][512] = op_W2^T
    float*          bc    = (float*)alloc((size_t)4*HID*4);                      // [4096]
    float*          gP    = (float*)alloc((size_t)4*NB*4*HID*4);                 // 4 split-K partials
    float*          oP    = (float*)alloc((size_t)4*NB*HID*4);                   // 4 partials for O1
    unsigned short* T     = (unsigned short*)alloc((size_t)NB*HOR*HID*2);        // t per step, [b][s][1024]
    unsigned short* th0   = (unsigned short*)alloc((size_t)NB*2*HID*2);          // [t | h0]
    // ---- zero-init region (contiguous; all sizes multiples of 256B) ----
    unsigned*       bar   = (unsigned*)alloc(256);                               // barrier cnt/gen
    unsigned short* xh0   = (unsigned short*)alloc((size_t)NB*(LAT+HID)*2);      // [prior | h0=0]
    unsigned short* hh1   = (unsigned short*)alloc((size_t)NB*2*HID*2);          // [h0 | h1]
    float*          c0    = (float*)alloc((size_t)NB*HID*4);
    float*          c1    = (float*)alloc((size_t)NB*HID*4);
    // ---- prologue scratch ----
    float* qbuf   = (float*)alloc((size_t)NB*HID*4);
    float* kbuf   = (float*)alloc((size_t)NSLOT*HID*4);
    float* vbuf   = (float*)alloc((size_t)NSLOT*HID*4);
    float* ctxbuf = (float*)alloc((size_t)NB*HID*4);
    float* ctxo   = (float*)alloc((size_t)NB*LAT*4);
    float* pgh    = (float*)alloc((size_t)NB*HID*4);

    const size_t zbytes = 256 + (size_t)NB*(LAT+HID)*2 + (size_t)NB*2*HID*2
                        + (size_t)NB*HID*4*2;
    hipMemsetAsync(bar, 0, zbytes, stream);

    const dim3 blk(256);

    // ---- pack weights to bf16 ----
    pack_mat<<<dim3((4*HID*LAT+255)/256), blk, 0, stream>>>(w_ih0, Wg0,        LAT+HID,  9, 4*HID*LAT);
    pack_mat<<<dim3((4*HID*HID+255)/256), blk, 0, stream>>>(w_hh0, Wg0+LAT,    LAT+HID, 10, 4*HID*HID);
    pack_mat<<<dim3((4*HID*HID+255)/256), blk, 0, stream>>>(w_hh0, Wg0c+HID,   2*HID,   10, 4*HID*HID);
    pack_mat<<<dim3((4*HID*HID+255)/256), blk, 0, stream>>>(w_ih1, Wg1,        2*HID,   10, 4*HID*HID);
    pack_mat<<<dim3((4*HID*HID+255)/256), blk, 0, stream>>>(w_hh1, Wg1+HID,    2*HID,   10, 4*HID*HID);
    pack_mat<<<dim3((HID*HID+255)/256),   blk, 0, stream>>>(op_W1, Wo1,        HID,     10, HID*HID);
    pack_mat<<<dim3((LAT*HID+255)/256),   blk, 0, stream>>>(op_W2, Wo2b,       HID,     10, LAT*HID);
    tpose_pack<<<dim3(HID*LAT/256), blk, 0, stream>>>(op_W2, W2T);
    bc_kernel<<<dim3(4*HID/256), blk, 0, stream>>>(w_ih0, op_b2, bc);

    // ---- Wc = Wih0 @ op_W2 -> bf16 into Wg0c left half ----
    // M=4096 (rows of Wg0 left half, lda=1536), N=1024 (rows of W2T), K=512
    mfma_std<128,128,0><<<dim3(HID/128, 4*HID/128), blk, 0, stream>>>(
        Wg0, LAT+HID, W2T, LAT, LAT, nullptr, nullptr, 0, Wg0c, 2*HID);

    // ---- prologue (fp32): attention read + prior ----
    gemm_tn<0><<<dim3(HID/64, 1), blk, 0, stream>>>(
        mem, HID, k_W, HID, HID, nullptr, 0, nullptr, 0, 0,
        k_b, kbuf, HID, nullptr, 0, NSLOT, HID);
    gemm_tn<0><<<dim3(HID/64, 1), blk, 0, stream>>>(
        mem, HID, v_W, HID, HID, nullptr, 0, nullptr, 0, 0,
        v_b, vbuf, HID, nullptr, 0, NSLOT, HID);
    gemm_tn<0><<<dim3(HID/64, NB/64), blk, 0, stream>>>(
        cs, LAT, q_W, LAT, LAT, nullptr, 0, nullptr, 0, 0,
        q_b, qbuf, HID, nullptr, 0, NB, HID);
    attn_kernel<<<dim3(NB), blk, 0, stream>>>(qbuf, kbuf, vbuf, ctxbuf);
    gemm_tn<0><<<dim3(LAT/64, NB/64), blk, 0, stream>>>(
        ctxbuf, HID, mo_W, HID, HID, nullptr, 0, nullptr, 0, 0,
        mo_b, ctxo, LAT, nullptr, 0, NB, LAT);
    gemm_tn<1><<<dim3(HID/64, NB/64), blk, 0, stream>>>(
        cs, LAT, pg_W1, HID, LAT, ctxo, LAT, pg_W1 + LAT, HID, LAT,
        pg_b1, pgh, HID, nullptr, 0, NB, HID);
    // prior -> fp32 output AND bf16 x0 (first 512 cols of xh0)
    gemm_tn<0><<<dim3(LAT/64, NB/64), blk, 0, stream>>>(
        pgh, HID, pg_W2, HID, HID, nullptr, 0, nullptr, 0, 0,
        pg_b2, prior_out, LAT, xh0, LAT+HID, NB, LAT);

    // ---- persistent rollout (64 LSTM steps), manual grid barrier ----
    RP prm;
    prm.xh0 = xh0;  prm.Wg0 = Wg0;  prm.Wg0c = Wg0c;  prm.Wg1 = Wg1;  prm.Wo1 = Wo1;
    prm.th0 = th0;  prm.hh1 = hh1;  prm.T = T;
    prm.gP = gP;    prm.oP = oP;    prm.c0 = c0;      prm.c1 = c1;
    prm.bih0 = b_ih0; prm.bhh0 = b_hh0; prm.bih1 = b_ih1; prm.bhh1 = b_hh1;
    prm.bc = bc;    prm.ob1 = op_b1;
    prm.cnt = bar;  prm.gen = bar + 1;
    rollout<<<dim3(NBLK), blk, 0, stream>>>(prm);

    // ---- batched pred = T @ op_W2^T + op_b2 -> out directly ([b][s][n]) ----
    mfma_std<128,128,1><<<dim3(LAT/128, NB*HOR/128), blk, 0, stream>>>(
        T, HID, Wo2b, HID, HID, op_b2, out, LAT, nullptr, 0);
}

// Round 6
// 7082.740 us; speedup vs baseline: 2.0431x; 2.0431x over previous
//
#include <hip/hip_runtime.h>
#include <cstddef>
#include <cstdint>

#define LAT 512
#define HID 1024
#define NSLOT 16
#define NB 256
#define HOR 64
#define NBLK 256

using short8  = __attribute__((ext_vector_type(8))) short;
using floatx4 = __attribute__((ext_vector_type(4))) float;

__device__ __forceinline__ float sigmoid_f(float x) { return 1.0f / (1.0f + __expf(-x)); }
__device__ __forceinline__ float tanh_f(float x) {
    float e = __expf(2.0f * x);
    return 1.0f - 2.0f / (e + 1.0f);
}
__device__ __forceinline__ unsigned short f2bf(float f) {
    union { float f; uint32_t u; } v; v.f = f;
    uint32_t u = v.u;
    return (unsigned short)((u + 0x7fffu + ((u >> 16) & 1u)) >> 16);
}
// async global->LDS, 16B per lane. LDS dest is wave-uniform base + lane*16.
__device__ __forceinline__ void async16(const void* g, void* l) {
    __builtin_amdgcn_global_load_lds(
        (const __attribute__((address_space(1))) unsigned int*)(unsigned long long)g,
        (__attribute__((address_space(3))) unsigned int*)(unsigned int)(unsigned long long)l,
        16, 0, 0);
}

// Grid barrier. KEY (R4 post-mortem): spin with RELAXED loads (no cache
// invalidate per poll) + ONE acquire fence after the flip. Arrivals are
// release-adds. All 256 blocks co-resident (1/CU; even 2/CU fits).
__device__ __forceinline__ void grid_bar(unsigned* bar)
{
    __syncthreads();
    if (threadIdx.x == 0) {
        unsigned* gen = bar;
        unsigned* cnt = bar + 16;   // separate 64B line
        const unsigned g = __hip_atomic_load(gen, __ATOMIC_RELAXED, __HIP_MEMORY_SCOPE_AGENT);
        const unsigned a = __hip_atomic_fetch_add(cnt, 1u, __ATOMIC_ACQ_REL, __HIP_MEMORY_SCOPE_AGENT);
        if (a == NBLK - 1u) {
            __hip_atomic_store(cnt, 0u, __ATOMIC_RELAXED, __HIP_MEMORY_SCOPE_AGENT);
            __hip_atomic_fetch_add(gen, 1u, __ATOMIC_RELEASE, __HIP_MEMORY_SCOPE_AGENT);
        } else {
            while (__hip_atomic_load(gen, __ATOMIC_RELAXED, __HIP_MEMORY_SCOPE_AGENT) == g)
                __builtin_amdgcn_s_sleep(16);
            __builtin_amdgcn_fence(__ATOMIC_ACQUIRE, "agent");
        }
    }
    __syncthreads();
}

// ---------------------------------------------------------------------------
// MFMA GEMM core: acc = A[m0:m0+BM, kbeg:kend] * W[n0:n0+BN, kbeg:kend]^T
// 256 threads = 4 waves (2x2), 16x16x32 bf16 MFMA, BK=64, async staging with
// XOR-chunk swizzle. Both A and W K-contiguous bf16.
// ---------------------------------------------------------------------------
template<int BM, int BN>
__device__ __forceinline__ void gemm_core(
    short* __restrict__ smem,
    const unsigned short* __restrict__ A, int lda,
    const unsigned short* __restrict__ W, int ldw,
    int m0, int n0, int kbeg, int kend,
    floatx4 (&acc)[BM/32][BN/32])
{
    constexpr int TM = BM/32, TN = BN/32;
    short* As = smem;
    short* Bs = smem + BM*64;
    const int t    = threadIdx.x;
    const int lane = t & 63;
    const int w    = t >> 6;
    const int wm   = w >> 1, wn = w & 1;
    const int r8 = lane >> 3;
    const int cx = (lane & 7) ^ r8;   // chunk c stored at in-row slot c^row
    const int q  = lane >> 4;
    const int ml = lane & 15;

    const floatx4 zf = {0.f,0.f,0.f,0.f};
    #pragma unroll
    for (int i = 0; i < TM; ++i)
        #pragma unroll
        for (int j = 0; j < TN; ++j) acc[i][j] = zf;

    for (int k0 = kbeg; k0 < kend; k0 += 64) {
        __syncthreads();
        #pragma unroll
        for (int u = 0; u < BM/32; ++u) {
            const int row = w*(BM/4) + u*8;
            async16(A + (size_t)(m0+row+r8)*lda + k0 + cx*8, &As[row*64]);
        }
        #pragma unroll
        for (int u = 0; u < BN/32; ++u) {
            const int row = w*(BN/4) + u*8;
            async16(W + (size_t)(n0+row+r8)*ldw + k0 + cx*8, &Bs[row*64]);
        }
        __syncthreads();
        #pragma unroll
        for (int s2 = 0; s2 < 2; ++s2) {
            short8 af[TM], bfr[TN];
            #pragma unroll
            for (int i = 0; i < TM; ++i) {
                const int m = wm*(BM/2) + i*16 + ml;
                af[i] = *(const short8*)&As[(m*8 + ((s2*4+q) ^ (m&7)))*8];
            }
            #pragma unroll
            for (int j = 0; j < TN; ++j) {
                const int n = wn*(BN/2) + j*16 + ml;
                bfr[j] = *(const short8*)&Bs[(n*8 + ((s2*4+q) ^ (n&7)))*8];
            }
            #pragma unroll
            for (int i = 0; i < TM; ++i)
                #pragma unroll
                for (int j = 0; j < TN; ++j)
                    acc[i][j] = __builtin_amdgcn_mfma_f32_16x16x32_bf16(af[i], bfr[j], acc[i][j], 0, 0, 0);
        }
    }
}

// Fused LSTM epilogue for a 64x64 gate tile (gate-interleaved cols: col=4u+g).
// acc -> padded LDS tile -> pointwise -> c (fp32) + h (bf16, 1-2 dests).
__device__ __forceinline__ void gate_epilogue(
    floatx4 (&acc)[2][2], float (*tile)[68],
    const float* __restrict__ bias,   // interleaved [4096]
    float* __restrict__ c, int m0, int u0,
    unsigned short* __restrict__ h1d, int ld1,
    unsigned short* __restrict__ h2d, int ld2)
{
    const int lane = threadIdx.x & 63, w = threadIdx.x >> 6;
    const int wm = w >> 1, wn = w & 1;
    const int q = lane >> 4, ml = lane & 15;
    #pragma unroll
    for (int i = 0; i < 2; ++i)
        #pragma unroll
        for (int j = 0; j < 2; ++j) {
            const int row = wm*32 + i*16 + q*4;
            const int col = wn*32 + j*16 + ml;
            #pragma unroll
            for (int r = 0; r < 4; ++r)
                tile[row + r][col] = acc[i][j][r];
        }
    __syncthreads();
    for (int e = threadIdx.x; e < 1024; e += 256) {
        const int row = e >> 4, u = e & 15;
        const float4 gv = *(const float4*)&tile[row][u*4];          // i,f,g,o pre-act
        const float4 bv = *(const float4*)(bias + (size_t)(u0+u)*4);
        const float i_ = sigmoid_f(gv.x + bv.x), f_ = sigmoid_f(gv.y + bv.y);
        const float g_ = tanh_f(gv.z + bv.z),    o_ = sigmoid_f(gv.w + bv.w);
        const size_t ci = (size_t)(m0 + row) * HID + u0 + u;
        const float cn = f_ * c[ci] + i_ * g_;
        c[ci] = cn;
        const unsigned short hb = f2bf(o_ * tanh_f(cn));
        h1d[(size_t)(m0+row)*ld1 + u0 + u] = hb;
        if (h2d) h2d[(size_t)(m0+row)*ld2 + u0 + u] = hb;
    }
    __syncthreads();
}

struct RP {
    const unsigned short *xh0, *Wg0, *Wg0c, *Wg1, *Wo1;
    unsigned short *th0, *hh1, *T;
    float *c0, *c1;
    const float *bs0, *bs0c, *bs1, *ob1;
    unsigned *bar;
};

// Persistent kernel: 64-step LSTM rollout, 3 grid barriers per step.
// Grid MUST be 256 blocks x 256 threads.
__global__ __launch_bounds__(256)
void rollout(RP P)
{
    __shared__ short smem[128*64];        // 16 KB staging (As+Bs for 64x64)
    __shared__ float tile[64][68];        // 17 KB padded pw tile (+68%32=4 de-bank)
    const int bid = blockIdx.x;
    // gates mapping: XCD-aware — xcd = bid&7 owns a 512-col weight slice.
    const int xcd = bid & 7, idx = bid >> 3;
    const int mtg = (idx & 3) * 64;
    const int ntg = (xcd * 8 + (idx >> 2)) * 64;
    // O1 mapping (64 active blocks over 4x16 tiles)
    const bool act1 = bid < 64;
    const int mt1 = (bid >> 4) * 64;
    const int nt1 = ((bid & 7) * 2 + ((bid >> 3) & 1)) * 64;

    floatx4 acc[2][2];

    for (int s = 0; s < HOR; ++s) {
        // P1: gates0 + pw0. s=0: [prior|h0]@[Wih0|Whh0]^T (K=1536)
        //                   s>0: [t|h0]@[Wc|Whh0]^T (K=2048)
        if (s == 0)
            gemm_core<64,64>(smem, P.xh0, 1536, P.Wg0, 1536, mtg, ntg, 0, 1536, acc);
        else
            gemm_core<64,64>(smem, P.th0, 2048, P.Wg0c, 2048, mtg, ntg, 0, 2048, acc);
        gate_epilogue(acc, tile, s == 0 ? P.bs0 : P.bs0c, P.c0, mtg, ntg >> 2,
                      P.th0 + 1024, 2048, P.hh1, 2048);
        grid_bar(P.bar);
        // P2: gates1 + pw1: [h0|h1]@[Wih1|Whh1]^T (K=2048)
        gemm_core<64,64>(smem, P.hh1, 2048, P.Wg1, 2048, mtg, ntg, 0, 2048, acc);
        gate_epilogue(acc, tile, P.bs1, P.c1, mtg, ntg >> 2,
                      P.hh1 + 1024, 2048, nullptr, 0);
        grid_bar(P.bar);
        // P3: t = relu(h1@Wo1^T + ob1) -> T[b][s][:] and th0 left half
        if (act1) {
            gemm_core<64,64>(smem, P.hh1 + 1024, 2048, P.Wo1, HID, mt1, nt1, 0, HID, acc);
            const int lane = threadIdx.x & 63, w = threadIdx.x >> 6;
            const int wm = w >> 1, wn = w & 1;
            const int q = lane >> 4, ml = lane & 15;
            #pragma unroll
            for (int i = 0; i < 2; ++i)
                #pragma unroll
                for (int j = 0; j < 2; ++j) {
                    const int col = nt1 + wn*32 + j*16 + ml;
                    const float bv = P.ob1[col];
                    #pragma unroll
                    for (int r = 0; r < 4; ++r) {
                        const int row = mt1 + wm*32 + i*16 + q*4 + r;
                        const unsigned short hb = f2bf(fmaxf(acc[i][j][r] + bv, 0.f));
                        P.T[((size_t)row*HOR + s)*HID + col] = hb;
                        P.th0[(size_t)row*2048 + col] = hb;
                    }
                }
        }
        grid_bar(P.bar);
    }
}

// ---------------------------------------------------------------------------
// Standalone MFMA GEMM: EPI 0: bf16 store, no bias (Wc); EPI 1: fp32+bias.
// ---------------------------------------------------------------------------
template<int BM, int BN, int EPI>
__global__ __launch_bounds__(256)
void mfma_std(const unsigned short* __restrict__ A, int lda,
              const unsigned short* __restrict__ W, int ldw, int K,
              const float* __restrict__ bias,
              float* __restrict__ Cf, int ldc,
              unsigned short* __restrict__ Cb, int ldcb)
{
    __shared__ short smem[(BM+BN)*64];
    floatx4 acc[BM/32][BN/32];
    const int m0 = blockIdx.y*BM, n0 = blockIdx.x*BN;
    gemm_core<BM,BN>(smem, A, lda, W, ldw, m0, n0, 0, K, acc);
    const int lane = threadIdx.x & 63;
    const int w    = threadIdx.x >> 6;
    const int wm = w>>1, wn = w&1;
    const int q = lane>>4, ml = lane&15;
    const int gmb = m0 + wm*(BM/2) + q*4;
    const int gnb = n0 + wn*(BN/2) + ml;
    #pragma unroll
    for (int i = 0; i < BM/32; ++i)
        #pragma unroll
        for (int j = 0; j < BN/32; ++j) {
            const int gm = gmb + i*16, gn = gnb + j*16;
            const float bv = (EPI == 1) ? bias[gn] : 0.f;
            #pragma unroll
            for (int r = 0; r < 4; ++r) {
                const float v = acc[i][j][r] + bv;
                if (EPI == 0) Cb[(size_t)(gm+r)*ldcb + gn] = f2bf(v);
                else          Cf[(size_t)(gm+r)*ldc  + gn] = v;
            }
        }
}

// gate-interleaved pack: out row p=4u+g <- src row g*1024+u  (4096 x K)
__global__ __launch_bounds__(256)
void pack_gate(const float* __restrict__ s, unsigned short* __restrict__ d,
               int ldd, int coloff, int kshift, int total)
{
    const int idx = blockIdx.x*256 + threadIdx.x;
    if (idx >= total) return;
    const int p = idx >> kshift;
    const int k = idx & ((1 << kshift) - 1);
    const int g = p & 3, u = p >> 2;
    d[(size_t)p*ldd + coloff + k] = f2bf(s[((size_t)(g*HID + u) << kshift) + k]);
}

// plain pack fp32 [N,K] -> bf16, leading dim ldd (K pow2)
__global__ __launch_bounds__(256)
void pack_mat(const float* __restrict__ s, unsigned short* __restrict__ d,
              int ldd, int kshift, int total)
{
    const int idx = blockIdx.x*256 + threadIdx.x;
    if (idx >= total) return;
    const int n = idx >> kshift;
    const int k = idx & ((1 << kshift) - 1);
    d[(size_t)n*ldd + k] = f2bf(s[idx]);
}

// op_W2 [512,1024] fp32 -> W2T [1024,512] bf16
__global__ __launch_bounds__(256)
void tpose_pack(const float* __restrict__ s, unsigned short* __restrict__ d)
{
    const int idx = blockIdx.x*256 + threadIdx.x;   // < 1024*512
    const int h = idx >> 9;
    const int l = idx & 511;
    d[idx] = f2bf(s[(size_t)l*HID + h]);
}

// interleaved biases: bs0=bih0+bhh0; bs0c=bs0+Wih0@ob2; bs1=bih1+bhh1
__global__ __launch_bounds__(256)
void bias_kernel(const float* __restrict__ bih0, const float* __restrict__ bhh0,
                 const float* __restrict__ bih1, const float* __restrict__ bhh1,
                 const float* __restrict__ wih0, const float* __restrict__ ob2,
                 float* __restrict__ bs0, float* __restrict__ bs0c,
                 float* __restrict__ bs1)
{
    const int p = blockIdx.x*256 + threadIdx.x;   // < 4096
    const int g = p & 3, u = p >> 2;
    const int srcn = g*HID + u;
    const float b0 = bih0[srcn] + bhh0[srcn];
    bs0[p] = b0;
    float a = 0.f;
    const float* wr = wih0 + (size_t)srcn * LAT;
    for (int l = 0; l < LAT; ++l) a += wr[l] * ob2[l];
    bs0c[p] = b0 + a;
    bs1[p] = bih1[srcn] + bhh1[srcn];
}

// ---------------------------------------------------------------------------
// fp32 prologue GEMM (attention + prior), one-time. C2 = optional bf16 copy.
// ---------------------------------------------------------------------------
template<int RELU>
__global__ __launch_bounds__(256)
void gemm_tn(const float* __restrict__ A1, int lda1,
             const float* __restrict__ W1, int ldw1, int K1,
             const float* __restrict__ A2, int lda2,
             const float* __restrict__ W2, int ldw2, int K2,
             const float* __restrict__ bias1,
             float* __restrict__ C, int ldc,
             unsigned short* __restrict__ C2, int ldc2,
             int M, int N)
{
    __shared__ float As[16][64];
    __shared__ float Ws[16][64];
    const int t   = threadIdx.x;
    const int bn0 = blockIdx.x * 64;
    const int bm0 = blockIdx.y * 64;
    const int tx  = t & 15;
    const int ty  = t >> 4;
    const int lr  = t >> 2;
    const int lc  = (t & 3) << 2;

    float acc[4][4] = {};

    for (int src = 0; src < 2; ++src) {
        const float* A = src ? A2 : A1;
        if (!A) continue;
        const float* W = src ? W2 : W1;
        const int lda = src ? lda2 : lda1;
        const int ldw = src ? ldw2 : ldw1;
        const int K   = src ? K2 : K1;
        for (int k0 = 0; k0 < K; k0 += 16) {
            float4 av = make_float4(0.f, 0.f, 0.f, 0.f);
            const int am = bm0 + lr;
            if (am < M) av = *(const float4*)(A + (size_t)am * lda + k0 + lc);
            const float4 wv = *(const float4*)(W + (size_t)(bn0 + lr) * ldw + k0 + lc);
            __syncthreads();
            As[lc + 0][lr] = av.x; As[lc + 1][lr] = av.y;
            As[lc + 2][lr] = av.z; As[lc + 3][lr] = av.w;
            Ws[lc + 0][lr] = wv.x; Ws[lc + 1][lr] = wv.y;
            Ws[lc + 2][lr] = wv.z; Ws[lc + 3][lr] = wv.w;
            __syncthreads();
            #pragma unroll
            for (int kk = 0; kk < 16; ++kk) {
                const float4 a = *(const float4*)&As[kk][ty * 4];
                const float4 b = *(const float4*)&Ws[kk][tx * 4];
                const float ar[4] = {a.x, a.y, a.z, a.w};
                const float br[4] = {b.x, b.y, b.z, b.w};
                #pragma unroll
                for (int i = 0; i < 4; ++i)
                    #pragma unroll
                    for (int j = 0; j < 4; ++j)
                        acc[i][j] = fmaf(ar[i], br[j], acc[i][j]);
            }
        }
    }

    const int n0 = bn0 + tx * 4;
    float bv[4] = {0.f, 0.f, 0.f, 0.f};
    if (bias1) {
        #pragma unroll
        for (int j = 0; j < 4; ++j) bv[j] += bias1[n0 + j];
    }
    #pragma unroll
    for (int i = 0; i < 4; ++i) {
        const int m = bm0 + ty * 4 + i;
        if (m < M) {
            float ov[4];
            #pragma unroll
            for (int j = 0; j < 4; ++j) {
                float v = acc[i][j] + bv[j];
                if (RELU) v = fmaxf(v, 0.f);
                ov[j] = v;
            }
            *(float4*)(C + (size_t)m * ldc + n0) = make_float4(ov[0], ov[1], ov[2], ov[3]);
            if (C2) {
                #pragma unroll
                for (int j = 0; j < 4; ++j)
                    C2[(size_t)m * ldc2 + n0 + j] = f2bf(ov[j]);
            }
        }
    }
}

__global__ __launch_bounds__(256)
void attn_kernel(const float* __restrict__ q, const float* __restrict__ k,
                 const float* __restrict__ v, float* __restrict__ ctx)
{
    __shared__ float red[NSLOT][4];
    __shared__ float wts[NSLOT];
    const int b = blockIdx.x;
    const int t = threadIdx.x;
    const float4 qv = *(const float4*)(q + (size_t)b * HID + t * 4);
    #pragma unroll
    for (int s = 0; s < NSLOT; ++s) {
        const float4 kv = *(const float4*)(k + (size_t)s * HID + t * 4);
        float p = qv.x * kv.x + qv.y * kv.y + qv.z * kv.z + qv.w * kv.w;
        #pragma unroll
        for (int off = 32; off > 0; off >>= 1) p += __shfl_down(p, off);
        if ((t & 63) == 0) red[s][t >> 6] = p;
    }
    __syncthreads();
    if (t == 0) {
        float sc[NSLOT];
        float mx = -1e30f;
        for (int s = 0; s < NSLOT; ++s) {
            sc[s] = (red[s][0] + red[s][1] + red[s][2] + red[s][3]) * 0.03125f;
            mx = fmaxf(mx, sc[s]);
        }
        float sum = 0.f;
        for (int s = 0; s < NSLOT; ++s) { const float e = __expf(sc[s] - mx); wts[s] = e; sum += e; }
        const float inv = 1.f / sum;
        for (int s = 0; s < NSLOT; ++s) wts[s] *= inv;
    }
    __syncthreads();
    float4 a = make_float4(0.f, 0.f, 0.f, 0.f);
    #pragma unroll
    for (int s = 0; s < NSLOT; ++s) {
        const float wv = wts[s];
        const float4 vv = *(const float4*)(v + (size_t)s * HID + t * 4);
        a.x += wv * vv.x; a.y += wv * vv.y; a.z += wv * vv.z; a.w += wv * vv.w;
    }
    *(float4*)(ctx + (size_t)b * HID + t * 4) = a;
}

extern "C" void kernel_launch(void* const* d_in, const int* in_sizes, int n_in,
                              void* d_out, int out_size, void* d_ws, size_t ws_size,
                              hipStream_t stream)
{
    const float* cs    = (const float*)d_in[0];
    const float* mem   = (const float*)d_in[2];
    const float* q_W   = (const float*)d_in[3];
    const float* q_b   = (const float*)d_in[4];
    const float* k_W   = (const float*)d_in[5];
    const float* k_b   = (const float*)d_in[6];
    const float* v_W   = (const float*)d_in[7];
    const float* v_b   = (const float*)d_in[8];
    const float* mo_W  = (const float*)d_in[9];
    const float* mo_b  = (const float*)d_in[10];
    const float* pg_W1 = (const float*)d_in[11];
    const float* pg_b1 = (const float*)d_in[12];
    const float* pg_W2 = (const float*)d_in[13];
    const float* pg_b2 = (const float*)d_in[14];
    const float* w_ih0 = (const float*)d_in[15];
    const float* w_hh0 = (const float*)d_in[16];
    const float* b_ih0 = (const float*)d_in[17];
    const float* b_hh0 = (const float*)d_in[18];
    const float* w_ih1 = (const float*)d_in[19];
    const float* w_hh1 = (const float*)d_in[20];
    const float* b_ih1 = (const float*)d_in[21];
    const float* b_hh1 = (const float*)d_in[22];
    const float* op_W1 = (const float*)d_in[23];
    const float* op_b1 = (const float*)d_in[24];
    const float* op_W2 = (const float*)d_in[25];
    const float* op_b2 = (const float*)d_in[26];

    float* out       = (float*)d_out;                       // [256*64*512] preds
    float* prior_out = out + (size_t)NB * HOR * LAT;        // [256*512]

    char* base = (char*)d_ws;
    auto alloc = [&](size_t bytes) { char* r = base; base += (bytes + 255) & ~255ull; return r; };

    unsigned short* Wg0   = (unsigned short*)alloc((size_t)4*HID*(LAT+HID)*2);   // [4096][1536] = [Wih0|Whh0] interleaved
    unsigned short* Wg0c  = (unsigned short*)alloc((size_t)4*HID*(2*HID)*2);     // [4096][2048] = [Wc|Whh0] interleaved
    unsigned short* Wg1   = (unsigned short*)alloc((size_t)4*HID*(2*HID)*2);     // [4096][2048] = [Wih1|Whh1] interleaved
    unsigned short* Wo1   = (unsigned short*)alloc((size_t)HID*HID*2);           // [1024][1024]
    unsigned short* Wo2b  = (unsigned short*)alloc((size_t)LAT*HID*2);           // [512][1024]
    unsigned short* W2T   = (unsigned short*)alloc((size_t)HID*LAT*2);           // [1024][512] = op_W2^T
    float*          bs0   = (float*)alloc((size_t)4*HID*4);                      // interleaved biases
    float*          bs0c  = (float*)alloc((size_t)4*HID*4);
    float*          bs1   = (float*)alloc((size_t)4*HID*4);
    unsigned short* T     = (unsigned short*)alloc((size_t)NB*HOR*HID*2);        // t per step, [b][s][1024]
    unsigned short* th0   = (unsigned short*)alloc((size_t)NB*2*HID*2);          // [t | h0]
    // ---- zero-init region (contiguous; all sizes multiples of 256B) ----
    unsigned*       bar   = (unsigned*)alloc(256);                               // barrier gen/cnt
    unsigned short* xh0   = (unsigned short*)alloc((size_t)NB*(LAT+HID)*2);      // [prior | h0=0]
    unsigned short* hh1   = (unsigned short*)alloc((size_t)NB*2*HID*2);          // [h0 | h1]
    float*          c0    = (float*)alloc((size_t)NB*HID*4);
    float*          c1    = (float*)alloc((size_t)NB*HID*4);
    // ---- prologue scratch ----
    float* qbuf   = (float*)alloc((size_t)NB*HID*4);
    float* kbuf   = (float*)alloc((size_t)NSLOT*HID*4);
    float* vbuf   = (float*)alloc((size_t)NSLOT*HID*4);
    float* ctxbuf = (float*)alloc((size_t)NB*HID*4);
    float* ctxo   = (float*)alloc((size_t)NB*LAT*4);
    float* pgh    = (float*)alloc((size_t)NB*HID*4);

    const size_t zbytes = 256 + (size_t)NB*(LAT+HID)*2 + (size_t)NB*2*HID*2
                        + (size_t)NB*HID*4*2;
    (void)hipMemsetAsync(bar, 0, zbytes, stream);

    const dim3 blk(256);

    // ---- pack weights to bf16 (gate matrices interleaved: row 4u+g) ----
    pack_gate<<<dim3(4*HID*LAT/256),  blk, 0, stream>>>(w_ih0, Wg0,       LAT+HID, 0,     9, 4*HID*LAT);
    pack_gate<<<dim3(4*HID*HID/256),  blk, 0, stream>>>(w_hh0, Wg0,       LAT+HID, LAT,  10, 4*HID*HID);
    pack_gate<<<dim3(4*HID*HID/256),  blk, 0, stream>>>(w_hh0, Wg0c,      2*HID,   HID,  10, 4*HID*HID);
    pack_gate<<<dim3(4*HID*HID/256),  blk, 0, stream>>>(w_ih1, Wg1,       2*HID,   0,    10, 4*HID*HID);
    pack_gate<<<dim3(4*HID*HID/256),  blk, 0, stream>>>(w_hh1, Wg1,       2*HID,   HID,  10, 4*HID*HID);
    pack_mat<<<dim3(HID*HID/256),     blk, 0, stream>>>(op_W1, Wo1,       HID,     10, HID*HID);
    pack_mat<<<dim3(LAT*HID/256),     blk, 0, stream>>>(op_W2, Wo2b,      HID,     10, LAT*HID);
    tpose_pack<<<dim3(HID*LAT/256),   blk, 0, stream>>>(op_W2, W2T);
    bias_kernel<<<dim3(4*HID/256),    blk, 0, stream>>>(b_ih0, b_hh0, b_ih1, b_hh1,
                                                        w_ih0, op_b2, bs0, bs0c, bs1);

    // ---- Wc = Wih0_i @ op_W2 -> bf16 into Wg0c left half (interleaved) ----
    mfma_std<128,128,0><<<dim3(HID/128, 4*HID/128), blk, 0, stream>>>(
        Wg0, LAT+HID, W2T, LAT, LAT, nullptr, nullptr, 0, Wg0c, 2*HID);

    // ---- prologue (fp32): attention read + prior ----
    gemm_tn<0><<<dim3(HID/64, 1), blk, 0, stream>>>(
        mem, HID, k_W, HID, HID, nullptr, 0, nullptr, 0, 0,
        k_b, kbuf, HID, nullptr, 0, NSLOT, HID);
    gemm_tn<0><<<dim3(HID/64, 1), blk, 0, stream>>>(
        mem, HID, v_W, HID, HID, nullptr, 0, nullptr, 0, 0,
        v_b, vbuf, HID, nullptr, 0, NSLOT, HID);
    gemm_tn<0><<<dim3(HID/64, NB/64), blk, 0, stream>>>(
        cs, LAT, q_W, LAT, LAT, nullptr, 0, nullptr, 0, 0,
        q_b, qbuf, HID, nullptr, 0, NB, HID);
    attn_kernel<<<dim3(NB), blk, 0, stream>>>(qbuf, kbuf, vbuf, ctxbuf);
    gemm_tn<0><<<dim3(LAT/64, NB/64), blk, 0, stream>>>(
        ctxbuf, HID, mo_W, HID, HID, nullptr, 0, nullptr, 0, 0,
        mo_b, ctxo, LAT, nullptr, 0, NB, LAT);
    gemm_tn<1><<<dim3(HID/64, NB/64), blk, 0, stream>>>(
        cs, LAT, pg_W1, HID, LAT, ctxo, LAT, pg_W1 + LAT, HID, LAT,
        pg_b1, pgh, HID, nullptr, 0, NB, HID);
    // prior -> fp32 output AND bf16 x0 (first 512 cols of xh0)
    gemm_tn<0><<<dim3(LAT/64, NB/64), blk, 0, stream>>>(
        pgh, HID, pg_W2, HID, HID, nullptr, 0, nullptr, 0, 0,
        pg_b2, prior_out, LAT, xh0, LAT+HID, NB, LAT);

    // ---- persistent rollout (64 LSTM steps, fused pw, 3 barriers/step) ----
    RP prm;
    prm.xh0 = xh0;  prm.Wg0 = Wg0;  prm.Wg0c = Wg0c;  prm.Wg1 = Wg1;  prm.Wo1 = Wo1;
    prm.th0 = th0;  prm.hh1 = hh1;  prm.T = T;
    prm.c0 = c0;    prm.c1 = c1;
    prm.bs0 = bs0;  prm.bs0c = bs0c;  prm.bs1 = bs1;  prm.ob1 = op_b1;
    prm.bar = bar;
    rollout<<<dim3(NBLK), blk, 0, stream>>>(prm);

    // ---- batched pred = T @ op_W2^T + op_b2 -> out directly ([b][s][n]) ----
    mfma_std<128,128,1><<<dim3(LAT/128, NB*HOR/128), blk, 0, stream>>>(
        T, HID, Wo2b, HID, HID, op_b2, out, LAT, nullptr, 0);
}

// Round 7
// 6115.640 us; speedup vs baseline: 2.3661x; 1.1581x over previous
//
#include <hip/hip_runtime.h>
#include <cstddef>
#include <cstdint>

#define LAT 512
#define HID 1024
#define NSLOT 16
#define NB 256
#define HOR 64
#define NBLK 256

using short8  = __attribute__((ext_vector_type(8))) short;
using floatx4 = __attribute__((ext_vector_type(4))) float;

__device__ __forceinline__ float sigmoid_f(float x) { return 1.0f / (1.0f + __expf(-x)); }
__device__ __forceinline__ float tanh_f(float x) {
    float e = __expf(2.0f * x);
    return 1.0f - 2.0f / (e + 1.0f);
}
__device__ __forceinline__ unsigned short f2bf(float f) {
    union { float f; uint32_t u; } v; v.f = f;
    uint32_t u = v.u;
    return (unsigned short)((u + 0x7fffu + ((u >> 16) & 1u)) >> 16);
}
// async global->LDS, 16B per lane. LDS dest is wave-uniform base + lane*16.
__device__ __forceinline__ void async16(const void* g, void* l) {
    __builtin_amdgcn_global_load_lds(
        (const __attribute__((address_space(1))) unsigned int*)(unsigned long long)g,
        (__attribute__((address_space(3))) unsigned int*)(unsigned int)(unsigned long long)l,
        16, 0, 0);
}

// Grid barrier: relaxed spin (no per-poll invalidate) + one acquire fence
// after the flip. All 256 blocks co-resident (1/CU).
__device__ __forceinline__ void grid_bar(unsigned* bar)
{
    __syncthreads();
    if (threadIdx.x == 0) {
        unsigned* gen = bar;
        unsigned* cnt = bar + 16;   // separate 64B line
        const unsigned g = __hip_atomic_load(gen, __ATOMIC_RELAXED, __HIP_MEMORY_SCOPE_AGENT);
        const unsigned a = __hip_atomic_fetch_add(cnt, 1u, __ATOMIC_ACQ_REL, __HIP_MEMORY_SCOPE_AGENT);
        if (a == NBLK - 1u) {
            __hip_atomic_store(cnt, 0u, __ATOMIC_RELAXED, __HIP_MEMORY_SCOPE_AGENT);
            __hip_atomic_fetch_add(gen, 1u, __ATOMIC_RELEASE, __HIP_MEMORY_SCOPE_AGENT);
        } else {
            while (__hip_atomic_load(gen, __ATOMIC_RELAXED, __HIP_MEMORY_SCOPE_AGENT) == g)
                __builtin_amdgcn_s_sleep(1);
            __builtin_amdgcn_fence(__ATOMIC_ACQUIRE, "agent");
        }
    }
    __syncthreads();
}

// ---------------------------------------------------------------------------
// DEEP-PIPELINED MFMA GEMM core (R7): DEPTH-ring of LDS k-buffers fed by
// global_load_lds; per-iter `s_waitcnt vmcnt(oldest)` + raw s_barrier (no
// full drain) — AITER-style. acc = A[m0:+BM, 0:K] * W[n0:+BN, 0:K]^T.
// 256 thr = 4 waves (2x2 over BMxBN), 16x16x32 bf16 MFMA, BK=64/iter.
// ---------------------------------------------------------------------------
template<int BM, int BN, int DEPTH>
__device__ __forceinline__ void gemm_core_pipe(
    short* smem,                       // ring: DEPTH * (BM+BN)*64 shorts
    const unsigned short* __restrict__ A, int lda,
    const unsigned short* __restrict__ W, int ldw,
    int m0, int n0, int K,
    floatx4 (&acc)[BM/32][BN/32])
{
    constexpr int TM = BM/32, TN = BN/32;
    constexpr int LPT = TM + TN;               // async16 per lane per iter
    constexpr int BUF = (BM + BN) * 64;        // shorts per ring slot
    // s_waitcnt simm16: vmcnt[3:0] | expcnt(0x7<<4) | lgkmcnt(0xF<<8)
    constexpr int WSTEADY = 0xF70 | ((DEPTH - 2) * LPT);

    const int t    = threadIdx.x;
    const int lane = t & 63;
    const int w    = t >> 6;
    const int wm   = w >> 1, wn = w & 1;
    const int r8 = lane >> 3;
    const int cx = (lane & 7) ^ r8;            // XOR-chunk swizzle
    const int q  = lane >> 4;
    const int ml = lane & 15;

    const floatx4 zf = {0.f,0.f,0.f,0.f};
    #pragma unroll
    for (int i = 0; i < TM; ++i)
        #pragma unroll
        for (int j = 0; j < TN; ++j) acc[i][j] = zf;

    auto issue = [&](int it) {
        short* As = smem + (it % DEPTH) * BUF;
        short* Bs = As + BM * 64;
        const int k0 = it * 64;
        #pragma unroll
        for (int u = 0; u < TM; ++u) {
            const int row = w*(BM/4) + u*8;
            async16(A + (size_t)(m0+row+r8)*lda + k0 + cx*8, &As[row*64]);
        }
        #pragma unroll
        for (int u = 0; u < TN; ++u) {
            const int row = w*(BN/4) + u*8;
            async16(W + (size_t)(n0+row+r8)*ldw + k0 + cx*8, &Bs[row*64]);
        }
    };
    auto compute = [&](int it) {
        short* As = smem + (it % DEPTH) * BUF;
        short* Bs = As + BM * 64;
        #pragma unroll
        for (int s2 = 0; s2 < 2; ++s2) {
            short8 af[TM], bfr[TN];
            #pragma unroll
            for (int i = 0; i < TM; ++i) {
                const int m = wm*(BM/2) + i*16 + ml;
                af[i] = *(const short8*)&As[(m*8 + ((s2*4+q) ^ (m&7)))*8];
            }
            #pragma unroll
            for (int j = 0; j < TN; ++j) {
                const int n = wn*(BN/2) + j*16 + ml;
                bfr[j] = *(const short8*)&Bs[(n*8 + ((s2*4+q) ^ (n&7)))*8];
            }
            #pragma unroll
            for (int i = 0; i < TM; ++i)
                #pragma unroll
                for (int j = 0; j < TN; ++j)
                    acc[i][j] = __builtin_amdgcn_mfma_f32_16x16x32_bf16(af[i], bfr[j], acc[i][j], 0, 0, 0);
        }
    };

    const int nIters = K / 64;
    const int pre = (DEPTH-1 < nIters) ? DEPTH-1 : nIters;
    for (int p = 0; p < pre; ++p) issue(p);
    int i = 0;
    for (; i < nIters - (DEPTH-1); ++i) {
        __builtin_amdgcn_s_waitcnt(WSTEADY);   // wait only iter-i's loads
        __builtin_amdgcn_s_barrier();          // raw barrier: no full drain
        compute(i);
        issue(i + DEPTH-1);                    // refill slot consumed at i-1
    }
    __builtin_amdgcn_s_waitcnt(0xF70);         // tail: drain all vmcnt
    __builtin_amdgcn_s_barrier();
    for (; i < nIters; ++i) compute(i);
}

// ---------------------------------------------------------------------------
// Legacy (non-pipelined) core for the one-shot standalone GEMMs.
// ---------------------------------------------------------------------------
template<int BM, int BN>
__device__ __forceinline__ void gemm_core(
    short* __restrict__ smem,
    const unsigned short* __restrict__ A, int lda,
    const unsigned short* __restrict__ W, int ldw,
    int m0, int n0, int kbeg, int kend,
    floatx4 (&acc)[BM/32][BN/32])
{
    constexpr int TM = BM/32, TN = BN/32;
    short* As = smem;
    short* Bs = smem + BM*64;
    const int t    = threadIdx.x;
    const int lane = t & 63;
    const int w    = t >> 6;
    const int wm   = w >> 1, wn = w & 1;
    const int r8 = lane >> 3;
    const int cx = (lane & 7) ^ r8;
    const int q  = lane >> 4;
    const int ml = lane & 15;

    const floatx4 zf = {0.f,0.f,0.f,0.f};
    #pragma unroll
    for (int i = 0; i < TM; ++i)
        #pragma unroll
        for (int j = 0; j < TN; ++j) acc[i][j] = zf;

    for (int k0 = kbeg; k0 < kend; k0 += 64) {
        __syncthreads();
        #pragma unroll
        for (int u = 0; u < TM; ++u) {
            const int row = w*(BM/4) + u*8;
            async16(A + (size_t)(m0+row+r8)*lda + k0 + cx*8, &As[row*64]);
        }
        #pragma unroll
        for (int u = 0; u < TN; ++u) {
            const int row = w*(BN/4) + u*8;
            async16(W + (size_t)(n0+row+r8)*ldw + k0 + cx*8, &Bs[row*64]);
        }
        __syncthreads();
        #pragma unroll
        for (int s2 = 0; s2 < 2; ++s2) {
            short8 af[TM], bfr[TN];
            #pragma unroll
            for (int i = 0; i < TM; ++i) {
                const int m = wm*(BM/2) + i*16 + ml;
                af[i] = *(const short8*)&As[(m*8 + ((s2*4+q) ^ (m&7)))*8];
            }
            #pragma unroll
            for (int j = 0; j < TN; ++j) {
                const int n = wn*(BN/2) + j*16 + ml;
                bfr[j] = *(const short8*)&Bs[(n*8 + ((s2*4+q) ^ (n&7)))*8];
            }
            #pragma unroll
            for (int i = 0; i < TM; ++i)
                #pragma unroll
                for (int j = 0; j < TN; ++j)
                    acc[i][j] = __builtin_amdgcn_mfma_f32_16x16x32_bf16(af[i], bfr[j], acc[i][j], 0, 0, 0);
        }
    }
}

// Fused LSTM epilogue for a 64x64 gate tile (gate-interleaved cols: col=4u+g).
// tile ALIASES the staging ring -> leading __syncthreads required.
__device__ __forceinline__ void gate_epilogue(
    floatx4 (&acc)[2][2], float (*tile)[68],
    const float* __restrict__ bias,   // interleaved [4096]
    float* __restrict__ c, int m0, int u0,
    unsigned short* __restrict__ h1d, int ld1,
    unsigned short* __restrict__ h2d, int ld2)
{
    __syncthreads();                  // ring buffers dead from here
    const int lane = threadIdx.x & 63, w = threadIdx.x >> 6;
    const int wm = w >> 1, wn = w & 1;
    const int q = lane >> 4, ml = lane & 15;
    #pragma unroll
    for (int i = 0; i < 2; ++i)
        #pragma unroll
        for (int j = 0; j < 2; ++j) {
            const int row = wm*32 + i*16 + q*4;
            const int col = wn*32 + j*16 + ml;
            #pragma unroll
            for (int r = 0; r < 4; ++r)
                tile[row + r][col] = acc[i][j][r];
        }
    __syncthreads();
    for (int e = threadIdx.x; e < 1024; e += 256) {
        const int row = e >> 4, u = e & 15;
        const float4 gv = *(const float4*)&tile[row][u*4];          // i,f,g,o
        const float4 bv = *(const float4*)(bias + (size_t)(u0+u)*4);
        const float i_ = sigmoid_f(gv.x + bv.x), f_ = sigmoid_f(gv.y + bv.y);
        const float g_ = tanh_f(gv.z + bv.z),    o_ = sigmoid_f(gv.w + bv.w);
        const size_t ci = (size_t)(m0 + row) * HID + u0 + u;
        const float cn = f_ * c[ci] + i_ * g_;
        c[ci] = cn;
        const unsigned short hb = f2bf(o_ * tanh_f(cn));
        h1d[(size_t)(m0+row)*ld1 + u0 + u] = hb;
        if (h2d) h2d[(size_t)(m0+row)*ld2 + u0 + u] = hb;
    }
    __syncthreads();
}

struct RP {
    const unsigned short *xh0, *Wg0, *Wg0c, *Wg1, *Wo1;
    unsigned short *th0, *hh1, *T;
    float *c0, *c1;
    const float *bs0, *bs0c, *bs1, *ob1;
    unsigned *bar;
};

// Persistent kernel: 64-step LSTM rollout, 3 grid barriers per step.
// Grid MUST be 256 blocks x 256 threads.
__global__ __launch_bounds__(256)
void rollout(RP P)
{
    // 64 KB: DEPTH=4 ring of (64+64)x64-short buffers; epilogue tile aliases.
    __shared__ __attribute__((aligned(16))) short smem[4 * 128 * 64];
    float (*tile)[68] = (float(*)[68])smem;

    const int bid = blockIdx.x;
    // gates mapping: XCD-aware — xcd = bid&7 owns a 512-col weight slice.
    const int xcd = bid & 7, idx = bid >> 3;
    const int mtg = (idx & 3) * 64;
    const int ntg = (xcd * 8 + (idx >> 2)) * 64;
    // O1 mapping: 32x32 tiles, all 256 blocks; XCD owns a 128-col Wo1 slice.
    const int mt1 = (bid >> 5) * 32;
    const int nt1 = ((bid & 7) * 4 + ((bid >> 3) & 3)) * 32;

    floatx4 acc[2][2];

    for (int s = 0; s < HOR; ++s) {
        // P1: gates0 + pw0. s=0: [prior|h0]@[Wih0|Whh0]^T (K=1536)
        //                   s>0: [t|h0]@[Wc|Whh0]^T (K=2048)
        if (s == 0)
            gemm_core_pipe<64,64,4>(smem, P.xh0, 1536, P.Wg0, 1536, mtg, ntg, 1536, acc);
        else
            gemm_core_pipe<64,64,4>(smem, P.th0, 2048, P.Wg0c, 2048, mtg, ntg, 2048, acc);
        gate_epilogue(acc, tile, s == 0 ? P.bs0 : P.bs0c, P.c0, mtg, ntg >> 2,
                      P.th0 + 1024, 2048, P.hh1, 2048);
        grid_bar(P.bar);
        // P2: gates1 + pw1: [h0|h1]@[Wih1|Whh1]^T (K=2048)
        gemm_core_pipe<64,64,4>(smem, P.hh1, 2048, P.Wg1, 2048, mtg, ntg, 2048, acc);
        gate_epilogue(acc, tile, P.bs1, P.c1, mtg, ntg >> 2,
                      P.hh1 + 1024, 2048, nullptr, 0);
        grid_bar(P.bar);
        // P3: t = relu(h1@Wo1^T + ob1) -> T[b][s][:] and th0 left half
        {
            floatx4 a1[1][1];
            gemm_core_pipe<32,32,4>(smem, P.hh1 + 1024, 2048, P.Wo1, HID, mt1, nt1, HID, a1);
            const int lane = threadIdx.x & 63, w = threadIdx.x >> 6;
            const int wm = w >> 1, wn = w & 1;
            const int q = lane >> 4, ml = lane & 15;
            const int col = nt1 + wn*16 + ml;
            const int rowb = mt1 + wm*16 + q*4;
            const float bv = P.ob1[col];
            #pragma unroll
            for (int r = 0; r < 4; ++r) {
                const int row = rowb + r;
                const unsigned short hb = f2bf(fmaxf(a1[0][0][r] + bv, 0.f));
                P.T[((size_t)row*HOR + s)*HID + col] = hb;
                P.th0[(size_t)row*2048 + col] = hb;
            }
        }
        grid_bar(P.bar);
    }
}

// ---------------------------------------------------------------------------
// Standalone MFMA GEMM: EPI 0: bf16 store, no bias (Wc); EPI 1: fp32+bias.
// ---------------------------------------------------------------------------
template<int BM, int BN, int EPI>
__global__ __launch_bounds__(256)
void mfma_std(const unsigned short* __restrict__ A, int lda,
              const unsigned short* __restrict__ W, int ldw, int K,
              const float* __restrict__ bias,
              float* __restrict__ Cf, int ldc,
              unsigned short* __restrict__ Cb, int ldcb)
{
    __shared__ short smem[(BM+BN)*64];
    floatx4 acc[BM/32][BN/32];
    const int m0 = blockIdx.y*BM, n0 = blockIdx.x*BN;
    gemm_core<BM,BN>(smem, A, lda, W, ldw, m0, n0, 0, K, acc);
    const int lane = threadIdx.x & 63;
    const int w    = threadIdx.x >> 6;
    const int wm = w>>1, wn = w&1;
    const int q = lane>>4, ml = lane&15;
    const int gmb = m0 + wm*(BM/2) + q*4;
    const int gnb = n0 + wn*(BN/2) + ml;
    #pragma unroll
    for (int i = 0; i < BM/32; ++i)
        #pragma unroll
        for (int j = 0; j < BN/32; ++j) {
            const int gm = gmb + i*16, gn = gnb + j*16;
            const float bv = (EPI == 1) ? bias[gn] : 0.f;
            #pragma unroll
            for (int r = 0; r < 4; ++r) {
                const float v = acc[i][j][r] + bv;
                if (EPI == 0) Cb[(size_t)(gm+r)*ldcb + gn] = f2bf(v);
                else          Cf[(size_t)(gm+r)*ldc  + gn] = v;
            }
        }
}

// gate-interleaved pack: out row p=4u+g <- src row g*1024+u  (4096 x K)
__global__ __launch_bounds__(256)
void pack_gate(const float* __restrict__ s, unsigned short* __restrict__ d,
               int ldd, int coloff, int kshift, int total)
{
    const int idx = blockIdx.x*256 + threadIdx.x;
    if (idx >= total) return;
    const int p = idx >> kshift;
    const int k = idx & ((1 << kshift) - 1);
    const int g = p & 3, u = p >> 2;
    d[(size_t)p*ldd + coloff + k] = f2bf(s[((size_t)(g*HID + u) << kshift) + k]);
}

// plain pack fp32 [N,K] -> bf16, leading dim ldd (K pow2)
__global__ __launch_bounds__(256)
void pack_mat(const float* __restrict__ s, unsigned short* __restrict__ d,
              int ldd, int kshift, int total)
{
    const int idx = blockIdx.x*256 + threadIdx.x;
    if (idx >= total) return;
    const int n = idx >> kshift;
    const int k = idx & ((1 << kshift) - 1);
    d[(size_t)n*ldd + k] = f2bf(s[idx]);
}

// op_W2 [512,1024] fp32 -> W2T [1024,512] bf16
__global__ __launch_bounds__(256)
void tpose_pack(const float* __restrict__ s, unsigned short* __restrict__ d)
{
    const int idx = blockIdx.x*256 + threadIdx.x;   // < 1024*512
    const int h = idx >> 9;
    const int l = idx & 511;
    d[idx] = f2bf(s[(size_t)l*HID + h]);
}

// interleaved biases: bs0=bih0+bhh0; bs0c=bs0+Wih0@ob2; bs1=bih1+bhh1
__global__ __launch_bounds__(256)
void bias_kernel(const float* __restrict__ bih0, const float* __restrict__ bhh0,
                 const float* __restrict__ bih1, const float* __restrict__ bhh1,
                 const float* __restrict__ wih0, const float* __restrict__ ob2,
                 float* __restrict__ bs0, float* __restrict__ bs0c,
                 float* __restrict__ bs1)
{
    const int p = blockIdx.x*256 + threadIdx.x;   // < 4096
    const int g = p & 3, u = p >> 2;
    const int srcn = g*HID + u;
    const float b0 = bih0[srcn] + bhh0[srcn];
    bs0[p] = b0;
    float a = 0.f;
    const float* wr = wih0 + (size_t)srcn * LAT;
    for (int l = 0; l < LAT; ++l) a += wr[l] * ob2[l];
    bs0c[p] = b0 + a;
    bs1[p] = bih1[srcn] + bhh1[srcn];
}

// ---------------------------------------------------------------------------
// fp32 prologue GEMM (attention + prior), one-time. C2 = optional bf16 copy.
// ---------------------------------------------------------------------------
template<int RELU>
__global__ __launch_bounds__(256)
void gemm_tn(const float* __restrict__ A1, int lda1,
             const float* __restrict__ W1, int ldw1, int K1,
             const float* __restrict__ A2, int lda2,
             const float* __restrict__ W2, int ldw2, int K2,
             const float* __restrict__ bias1,
             float* __restrict__ C, int ldc,
             unsigned short* __restrict__ C2, int ldc2,
             int M, int N)
{
    __shared__ float As[16][64];
    __shared__ float Ws[16][64];
    const int t   = threadIdx.x;
    const int bn0 = blockIdx.x * 64;
    const int bm0 = blockIdx.y * 64;
    const int tx  = t & 15;
    const int ty  = t >> 4;
    const int lr  = t >> 2;
    const int lc  = (t & 3) << 2;

    float acc[4][4] = {};

    for (int src = 0; src < 2; ++src) {
        const float* A = src ? A2 : A1;
        if (!A) continue;
        const float* W = src ? W2 : W1;
        const int lda = src ? lda2 : lda1;
        const int ldw = src ? ldw2 : ldw1;
        const int K   = src ? K2 : K1;
        for (int k0 = 0; k0 < K; k0 += 16) {
            float4 av = make_float4(0.f, 0.f, 0.f, 0.f);
            const int am = bm0 + lr;
            if (am < M) av = *(const float4*)(A + (size_t)am * lda + k0 + lc);
            const float4 wv = *(const float4*)(W + (size_t)(bn0 + lr) * ldw + k0 + lc);
            __syncthreads();
            As[lc + 0][lr] = av.x; As[lc + 1][lr] = av.y;
            As[lc + 2][lr] = av.z; As[lc + 3][lr] = av.w;
            Ws[lc + 0][lr] = wv.x; Ws[lc + 1][lr] = wv.y;
            Ws[lc + 2][lr] = wv.z; Ws[lc + 3][lr] = wv.w;
            __syncthreads();
            #pragma unroll
            for (int kk = 0; kk < 16; ++kk) {
                const float4 a = *(const float4*)&As[kk][ty * 4];
                const float4 b = *(const float4*)&Ws[kk][tx * 4];
                const float ar[4] = {a.x, a.y, a.z, a.w};
                const float br[4] = {b.x, b.y, b.z, b.w};
                #pragma unroll
                for (int i = 0; i < 4; ++i)
                    #pragma unroll
                    for (int j = 0; j < 4; ++j)
                        acc[i][j] = fmaf(ar[i], br[j], acc[i][j]);
            }
        }
    }

    const int n0 = bn0 + tx * 4;
    float bv[4] = {0.f, 0.f, 0.f, 0.f};
    if (bias1) {
        #pragma unroll
        for (int j = 0; j < 4; ++j) bv[j] += bias1[n0 + j];
    }
    #pragma unroll
    for (int i = 0; i < 4; ++i) {
        const int m = bm0 + ty * 4 + i;
        if (m < M) {
            float ov[4];
            #pragma unroll
            for (int j = 0; j < 4; ++j) {
                float v = acc[i][j] + bv[j];
                if (RELU) v = fmaxf(v, 0.f);
                ov[j] = v;
            }
            *(float4*)(C + (size_t)m * ldc + n0) = make_float4(ov[0], ov[1], ov[2], ov[3]);
            if (C2) {
                #pragma unroll
                for (int j = 0; j < 4; ++j)
                    C2[(size_t)m * ldc2 + n0 + j] = f2bf(ov[j]);
            }
        }
    }
}

__global__ __launch_bounds__(256)
void attn_kernel(const float* __restrict__ q, const float* __restrict__ k,
                 const float* __restrict__ v, float* __restrict__ ctx)
{
    __shared__ float red[NSLOT][4];
    __shared__ float wts[NSLOT];
    const int b = blockIdx.x;
    const int t = threadIdx.x;
    const float4 qv = *(const float4*)(q + (size_t)b * HID + t * 4);
    #pragma unroll
    for (int s = 0; s < NSLOT; ++s) {
        const float4 kv = *(const float4*)(k + (size_t)s * HID + t * 4);
        float p = qv.x * kv.x + qv.y * kv.y + qv.z * kv.z + qv.w * kv.w;
        #pragma unroll
        for (int off = 32; off > 0; off >>= 1) p += __shfl_down(p, off);
        if ((t & 63) == 0) red[s][t >> 6] = p;
    }
    __syncthreads();
    if (t == 0) {
        float sc[NSLOT];
        float mx = -1e30f;
        for (int s = 0; s < NSLOT; ++s) {
            sc[s] = (red[s][0] + red[s][1] + red[s][2] + red[s][3]) * 0.03125f;
            mx = fmaxf(mx, sc[s]);
        }
        float sum = 0.f;
        for (int s = 0; s < NSLOT; ++s) { const float e = __expf(sc[s] - mx); wts[s] = e; sum += e; }
        const float inv = 1.f / sum;
        for (int s = 0; s < NSLOT; ++s) wts[s] *= inv;
    }
    __syncthreads();
    float4 a = make_float4(0.f, 0.f, 0.f, 0.f);
    #pragma unroll
    for (int s = 0; s < NSLOT; ++s) {
        const float wv = wts[s];
        const float4 vv = *(const float4*)(v + (size_t)s * HID + t * 4);
        a.x += wv * vv.x; a.y += wv * vv.y; a.z += wv * vv.z; a.w += wv * vv.w;
    }
    *(float4*)(ctx + (size_t)b * HID + t * 4) = a;
}

extern "C" void kernel_launch(void* const* d_in, const int* in_sizes, int n_in,
                              void* d_out, int out_size, void* d_ws, size_t ws_size,
                              hipStream_t stream)
{
    const float* cs    = (const float*)d_in[0];
    const float* mem   = (const float*)d_in[2];
    const float* q_W   = (const float*)d_in[3];
    const float* q_b   = (const float*)d_in[4];
    const float* k_W   = (const float*)d_in[5];
    const float* k_b   = (const float*)d_in[6];
    const float* v_W   = (const float*)d_in[7];
    const float* v_b   = (const float*)d_in[8];
    const float* mo_W  = (const float*)d_in[9];
    const float* mo_b  = (const float*)d_in[10];
    const float* pg_W1 = (const float*)d_in[11];
    const float* pg_b1 = (const float*)d_in[12];
    const float* pg_W2 = (const float*)d_in[13];
    const float* pg_b2 = (const float*)d_in[14];
    const float* w_ih0 = (const float*)d_in[15];
    const float* w_hh0 = (const float*)d_in[16];
    const float* b_ih0 = (const float*)d_in[17];
    const float* b_hh0 = (const float*)d_in[18];
    const float* w_ih1 = (const float*)d_in[19];
    const float* w_hh1 = (const float*)d_in[20];
    const float* b_ih1 = (const float*)d_in[21];
    const float* b_hh1 = (const float*)d_in[22];
    const float* op_W1 = (const float*)d_in[23];
    const float* op_b1 = (const float*)d_in[24];
    const float* op_W2 = (const float*)d_in[25];
    const float* op_b2 = (const float*)d_in[26];

    float* out       = (float*)d_out;                       // [256*64*512] preds
    float* prior_out = out + (size_t)NB * HOR * LAT;        // [256*512]

    char* base = (char*)d_ws;
    auto alloc = [&](size_t bytes) { char* r = base; base += (bytes + 255) & ~255ull; return r; };

    unsigned short* Wg0   = (unsigned short*)alloc((size_t)4*HID*(LAT+HID)*2);   // [4096][1536] = [Wih0|Whh0] interleaved
    unsigned short* Wg0c  = (unsigned short*)alloc((size_t)4*HID*(2*HID)*2);     // [4096][2048] = [Wc|Whh0] interleaved
    unsigned short* Wg1   = (unsigned short*)alloc((size_t)4*HID*(2*HID)*2);     // [4096][2048] = [Wih1|Whh1] interleaved
    unsigned short* Wo1   = (unsigned short*)alloc((size_t)HID*HID*2);           // [1024][1024]
    unsigned short* Wo2b  = (unsigned short*)alloc((size_t)LAT*HID*2);           // [512][1024]
    unsigned short* W2T   = (unsigned short*)alloc((size_t)HID*LAT*2);           // [1024][512] = op_W2^T
    float*          bs0   = (float*)alloc((size_t)4*HID*4);                      // interleaved biases
    float*          bs0c  = (float*)alloc((size_t)4*HID*4);
    float*          bs1   = (float*)alloc((size_t)4*HID*4);
    unsigned short* T     = (unsigned short*)alloc((size_t)NB*HOR*HID*2);        // t per step, [b][s][1024]
    unsigned short* th0   = (unsigned short*)alloc((size_t)NB*2*HID*2);          // [t | h0]
    // ---- zero-init region (contiguous; all sizes multiples of 256B) ----
    unsigned*       bar   = (unsigned*)alloc(256);                               // barrier gen/cnt
    unsigned short* xh0   = (unsigned short*)alloc((size_t)NB*(LAT+HID)*2);      // [prior | h0=0]
    unsigned short* hh1   = (unsigned short*)alloc((size_t)NB*2*HID*2);          // [h0 | h1]
    float*          c0    = (float*)alloc((size_t)NB*HID*4);
    float*          c1    = (float*)alloc((size_t)NB*HID*4);
    // ---- prologue scratch ----
    float* qbuf   = (float*)alloc((size_t)NB*HID*4);
    float* kbuf   = (float*)alloc((size_t)NSLOT*HID*4);
    float* vbuf   = (float*)alloc((size_t)NSLOT*HID*4);
    float* ctxbuf = (float*)alloc((size_t)NB*HID*4);
    float* ctxo   = (float*)alloc((size_t)NB*LAT*4);
    float* pgh    = (float*)alloc((size_t)NB*HID*4);

    const size_t zbytes = 256 + (size_t)NB*(LAT+HID)*2 + (size_t)NB*2*HID*2
                        + (size_t)NB*HID*4*2;
    (void)hipMemsetAsync(bar, 0, zbytes, stream);

    const dim3 blk(256);

    // ---- pack weights to bf16 (gate matrices interleaved: row 4u+g) ----
    pack_gate<<<dim3(4*HID*LAT/256),  blk, 0, stream>>>(w_ih0, Wg0,       LAT+HID, 0,     9, 4*HID*LAT);
    pack_gate<<<dim3(4*HID*HID/256),  blk, 0, stream>>>(w_hh0, Wg0,       LAT+HID, LAT,  10, 4*HID*HID);
    pack_gate<<<dim3(4*HID*HID/256),  blk, 0, stream>>>(w_hh0, Wg0c,      2*HID,   HID,  10, 4*HID*HID);
    pack_gate<<<dim3(4*HID*HID/256),  blk, 0, stream>>>(w_ih1, Wg1,       2*HID,   0,    10, 4*HID*HID);
    pack_gate<<<dim3(4*HID*HID/256),  blk, 0, stream>>>(w_hh1, Wg1,       2*HID,   HID,  10, 4*HID*HID);
    pack_mat<<<dim3(HID*HID/256),     blk, 0, stream>>>(op_W1, Wo1,       HID,     10, HID*HID);
    pack_mat<<<dim3(LAT*HID/256),     blk, 0, stream>>>(op_W2, Wo2b,      HID,     10, LAT*HID);
    tpose_pack<<<dim3(HID*LAT/256),   blk, 0, stream>>>(op_W2, W2T);
    bias_kernel<<<dim3(4*HID/256),    blk, 0, stream>>>(b_ih0, b_hh0, b_ih1, b_hh1,
                                                        w_ih0, op_b2, bs0, bs0c, bs1);

    // ---- Wc = Wih0_i @ op_W2 -> bf16 into Wg0c left half (interleaved) ----
    mfma_std<128,128,0><<<dim3(HID/128, 4*HID/128), blk, 0, stream>>>(
        Wg0, LAT+HID, W2T, LAT, LAT, nullptr, nullptr, 0, Wg0c, 2*HID);

    // ---- prologue (fp32): attention read + prior ----
    gemm_tn<0><<<dim3(HID/64, 1), blk, 0, stream>>>(
        mem, HID, k_W, HID, HID, nullptr, 0, nullptr, 0, 0,
        k_b, kbuf, HID, nullptr, 0, NSLOT, HID);
    gemm_tn<0><<<dim3(HID/64, 1), blk, 0, stream>>>(
        mem, HID, v_W, HID, HID, nullptr, 0, nullptr, 0, 0,
        v_b, vbuf, HID, nullptr, 0, NSLOT, HID);
    gemm_tn<0><<<dim3(HID/64, NB/64), blk, 0, stream>>>(
        cs, LAT, q_W, LAT, LAT, nullptr, 0, nullptr, 0, 0,
        q_b, qbuf, HID, nullptr, 0, NB, HID);
    attn_kernel<<<dim3(NB), blk, 0, stream>>>(qbuf, kbuf, vbuf, ctxbuf);
    gemm_tn<0><<<dim3(LAT/64, NB/64), blk, 0, stream>>>(
        ctxbuf, HID, mo_W, HID, HID, nullptr, 0, nullptr, 0, 0,
        mo_b, ctxo, LAT, nullptr, 0, NB, LAT);
    gemm_tn<1><<<dim3(HID/64, NB/64), blk, 0, stream>>>(
        cs, LAT, pg_W1, HID, LAT, ctxo, LAT, pg_W1 + LAT, HID, LAT,
        pg_b1, pgh, HID, nullptr, 0, NB, HID);
    // prior -> fp32 output AND bf16 x0 (first 512 cols of xh0)
    gemm_tn<0><<<dim3(LAT/64, NB/64), blk, 0, stream>>>(
        pgh, HID, pg_W2, HID, HID, nullptr, 0, nullptr, 0, 0,
        pg_b2, prior_out, LAT, xh0, LAT+HID, NB, LAT);

    // ---- persistent rollout (64 LSTM steps, pipelined K-loops) ----
    RP prm;
    prm.xh0 = xh0;  prm.Wg0 = Wg0;  prm.Wg0c = Wg0c;  prm.Wg1 = Wg1;  prm.Wo1 = Wo1;
    prm.th0 = th0;  prm.hh1 = hh1;  prm.T = T;
    prm.c0 = c0;    prm.c1 = c1;
    prm.bs0 = bs0;  prm.bs0c = bs0c;  prm.bs1 = bs1;  prm.ob1 = op_b1;
    prm.bar = bar;
    rollout<<<dim3(NBLK), blk, 0, stream>>>(prm);

    // ---- batched pred = T @ op_W2^T + op_b2 -> out directly ([b][s][n]) ----
    mfma_std<128,128,1><<<dim3(LAT/128, NB*HOR/128), blk, 0, stream>>>(
        T, HID, Wo2b, HID, HID, op_b2, out, LAT, nullptr, 0);
}